// Round 7
// baseline (1139.795 us; speedup 1.0000x reference)
//
#include <hip/hip_runtime.h>

typedef __attribute__((ext_vector_type(8))) short sh8;       // 8 bf16 (4 VGPRs)
typedef __attribute__((ext_vector_type(4))) float f32x4;

#define E_EDGES 100000
#define E_PAD   100096   // 1564 * 64
#define N_NODES 20000

__device__ __forceinline__ unsigned short f2bf(float f) {
  union { float f; unsigned int u; } v; v.f = f;
  unsigned int r = v.u + 0x7FFFu + ((v.u >> 16) & 1u);   // RNE
  return (unsigned short)(r >> 16);
}

__device__ __forceinline__ void async16(const void* g, void* l) {
  __builtin_amdgcn_global_load_lds((const __attribute__((address_space(1))) unsigned int*)g,
                                   (__attribute__((address_space(3))) unsigned int*)l,
                                   16, 0, 0);
}

// ---- w2 (f32 [1024][1024] k-major) -> w2t (bf16 [n][k]) ----
__global__ void transpose_w2_kernel(const float* __restrict__ w2, unsigned short* __restrict__ w2t) {
  __shared__ float tile[32][33];
  int b = blockIdx.x;
  int bx = b & 31, by = b >> 5;
  int lx = threadIdx.x & 31, ly = threadIdx.x >> 5;
#pragma unroll
  for (int j = 0; j < 4; ++j)
    tile[ly + j*8][lx] = w2[(by*32 + ly + j*8)*1024 + bx*32 + lx];
  __syncthreads();
#pragma unroll
  for (int j = 0; j < 4; ++j)
    w2t[(size_t)(bx*32 + ly + j*8)*1024 + by*32 + lx] = f2bf(tile[lx][ly + j*8]);
}

// ---- h1 = relu(ea @ w1 + b1) -> bf16 [E_PAD][1024]; 16 edges per block ----
__global__ __launch_bounds__(256)
void edge_mlp1_kernel(const float* __restrict__ ea, const float* __restrict__ w1,
                      const float* __restrict__ b1, unsigned short* __restrict__ h1) {
  __shared__ float eas[16][16];
  const int tid = threadIdx.x;
  const int e0 = blockIdx.x * 16;
  {
    int g = tid >> 4, d = tid & 15;
    int ge = e0 + g;
    eas[g][d] = (ge < E_EDGES) ? ea[(size_t)ge*16 + d] : 0.f;
  }
  __syncthreads();
  const int c0 = tid * 4;
  float4 bb = *(const float4*)(b1 + c0);
  float4 acc[16];
#pragma unroll
  for (int g = 0; g < 16; ++g) acc[g] = bb;
#pragma unroll
  for (int d = 0; d < 16; ++d) {
    float4 w = *(const float4*)(w1 + (size_t)d*1024 + c0);
#pragma unroll
    for (int g = 0; g < 16; ++g) {
      float ev = eas[g][d];
      acc[g].x += ev*w.x; acc[g].y += ev*w.y; acc[g].z += ev*w.z; acc[g].w += ev*w.w;
    }
  }
#pragma unroll
  for (int g = 0; g < 16; ++g) {
    ushort4 o;
    if (e0 + g < E_EDGES) {
      o.x = f2bf(fmaxf(acc[g].x, 0.f)); o.y = f2bf(fmaxf(acc[g].y, 0.f));
      o.z = f2bf(fmaxf(acc[g].z, 0.f)); o.w = f2bf(fmaxf(acc[g].w, 0.f));
    } else {
      o.x = o.y = o.z = o.w = 0;
    }
    *(ushort4*)(h1 + (size_t)(e0 + g)*1024 + c0) = o;
  }
}

// ---- cnt[dst] += 1 ----
__global__ void count_kernel(const int* __restrict__ dst, float* __restrict__ cnt) {
  int t = blockIdx.x*256 + threadIdx.x;
  if (t < E_EDGES) atomicAdd(&cnt[dst[t]], 1.0f);
}

// ==== block = 64 edges x FULL K=1024 x FULL N=1024. A staged once in 128KB
// LDS (XOR-swizzled); B read per-fragment from L2 (2MB, resident) — no B
// staging, no barriers in the K-loop. 8 waves (1M x 8N), acc[4][8]. ====
__global__ __launch_bounds__(512, 1)
void gemm_scatter_kernel(const unsigned short* __restrict__ h1,
                         const unsigned short* __restrict__ w2t,
                         const float* __restrict__ b2,
                         const float* __restrict__ xin,
                         const int* __restrict__ src,
                         const int* __restrict__ dst,
                         float* __restrict__ agg) {
  __shared__ __align__(16) unsigned char lds[131072];       // A [64][1024] bf16 swizzled
  float* msgw = (float*)lds;                                // epilogue: [8][64*33] = 67584 B
  float (*xg)[32] = (float (*)[32])(lds + 67584);           // 8 KB
  int* dsts = (int*)(lds + 75776);                          // 256 B

  const int tid  = threadIdx.x;
  const int wave = tid >> 6, lane = tid & 63;
  const int lr = lane >> 4, lc = lane & 15;
  const int e0 = blockIdx.x * 64;

  // ---- stage A = h1[e0..e0+64)[:] into LDS, linear dest + inverse-swizzled src ----
  {
    const unsigned short* Ag = h1 + (size_t)e0 * 1024;
#pragma unroll
    for (int it = 0; it < 16; ++it) {
      int X  = it*8192 + tid*16;           // linear LDS byte offset
      int r  = X >> 11;                    // row 0..63
      int c0 = (X & 2047) >> 1;            // element col (multiple of 8)
      int cs = c0 ^ ((r & 7) << 3);        // pre-swizzled source col
      async16(Ag + (size_t)r*1024 + cs, lds + X);
    }
  }
  __syncthreads();                          // drains vmcnt: A resident

  f32x4 acc[4][8];
#pragma unroll
  for (int m = 0; m < 4; ++m)
#pragma unroll
    for (int n = 0; n < 8; ++n) acc[m][n] = (f32x4){0.f, 0.f, 0.f, 0.f};

  const int swzb = (lc & 7) << 4;
  const unsigned short* bb = w2t + (size_t)(wave*128 + lc)*1024 + lr*8;
  const char* Ab = (const char*)lds;

  for (int kt = 0; kt < 16; ++kt) {
#pragma unroll
    for (int kk = 0; kk < 2; ++kk) {
      sh8 bfr[8], afr[4];
#pragma unroll
      for (int ni = 0; ni < 8; ++ni)
        bfr[ni] = *(const sh8*)(bb + ni*16384 + kt*64 + kk*32);   // L2-resident B
#pragma unroll
      for (int m = 0; m < 4; ++m)
        afr[m] = *(const sh8*)(Ab + (m*16 + lc)*2048 + ((kt*128 + kk*64 + lr*16) ^ swzb));
      __builtin_amdgcn_s_setprio(1);
#pragma unroll
      for (int m = 0; m < 4; ++m)
#pragma unroll
        for (int ni = 0; ni < 8; ++ni)
          acc[m][ni] = __builtin_amdgcn_mfma_f32_16x16x32_bf16(afr[m], bfr[ni], acc[m][ni], 0, 0, 0);
      __builtin_amdgcn_s_setprio(0);
    }
  }

  // ---- epilogue ----
  __syncthreads();                          // all A LDS reads done; alias region
  {
    int e = tid >> 3, q = tid & 7;          // 64 edges x 8 quads
    int ge = e0 + e;
    float4 v = make_float4(0.f, 0.f, 0.f, 0.f);
    if (ge < E_EDGES) v = *(const float4*)(xin + (size_t)src[ge]*32 + q*4);
    *(float4*)&xg[e][q*4] = v;
    if (tid < 64) dsts[tid] = (e0 + tid < E_EDGES) ? dst[e0 + tid] : -1;
  }
  float b2c[8];
#pragma unroll
  for (int ni = 0; ni < 8; ++ni) b2c[ni] = b2[wave*128 + ni*16 + lc];
  __syncthreads();

  // msg partial: col = wave*128 + ni*16 + lc -> i = wave*4 + (ni>>1), o = (ni&1)*16 + lc
  {
    float* mw = msgw + wave*(64*33);
#pragma unroll
    for (int m = 0; m < 4; ++m)
#pragma unroll
      for (int r = 0; r < 4; ++r) {
        int e = m*16 + lr*4 + r;
        float x0 = xg[e][wave*4 + 0], x1 = xg[e][wave*4 + 1];
        float x2 = xg[e][wave*4 + 2], x3 = xg[e][wave*4 + 3];
        float ms0 = (acc[m][0][r] + b2c[0])*x0 + (acc[m][2][r] + b2c[2])*x1
                  + (acc[m][4][r] + b2c[4])*x2 + (acc[m][6][r] + b2c[6])*x3;
        float ms1 = (acc[m][1][r] + b2c[1])*x0 + (acc[m][3][r] + b2c[3])*x1
                  + (acc[m][5][r] + b2c[5])*x2 + (acc[m][7][r] + b2c[7])*x3;
        mw[e*33 + lc]      = ms0;
        mw[e*33 + lc + 16] = ms1;
      }
  }
  __syncthreads();
  for (int t = tid; t < 64*32; t += 512) {
    int e = t >> 5, o = t & 31;
    int dn = dsts[e];
    if (dn >= 0) {
      float s = 0.f;
#pragma unroll
      for (int w = 0; w < 8; ++w) s += msgw[w*(64*33) + e*33 + o];
      atomicAdd(&agg[(size_t)dn*32 + o], s);
    }
  }
}

// ---- node update: out = relu(agg/max(cnt,1) + x@root + bias) ----
__global__ void node_update_kernel(const float* __restrict__ agg, const float* __restrict__ cnt,
                                   const float* __restrict__ xin, const float* __restrict__ root,
                                   const float* __restrict__ bias, float* __restrict__ outp) {
  int t = blockIdx.x*256 + threadIdx.x;
  if (t >= N_NODES*32) return;
  int n = t >> 5, i = t & 31;
  const float* xr = xin + (size_t)n*32;
  float s = bias[i];
#pragma unroll
  for (int j = 0; j < 32; ++j) s += xr[j]*root[j*32 + i];
  float c = cnt[n]; c = c > 1.f ? c : 1.f;
  float v = agg[t]/c + s;
  outp[t] = fmaxf(v, 0.f);
}

// ---- final: out = h @ lin_w + lin_b ----
__global__ void final_linear_kernel(const float* __restrict__ h, const float* __restrict__ lw,
                                    const float* __restrict__ lb, float* __restrict__ out) {
  int t = blockIdx.x*256 + threadIdx.x;
  if (t >= N_NODES*10) return;
  int n = t / 10, k = t % 10;
  const float* hr = h + (size_t)n*32;
  float s = lb[k];
#pragma unroll
  for (int i = 0; i < 32; ++i) s += hr[i]*lw[i*10 + k];
  out[t] = s;
}

extern "C" void kernel_launch(void* const* d_in, const int* in_sizes, int n_in,
                              void* d_out, int out_size, void* d_ws, size_t ws_size,
                              hipStream_t stream) {
  const float* x     = (const float*)d_in[0];
  const int*   ei    = (const int*)d_in[1];
  const float* ea    = (const float*)d_in[2];
  const float* e1w1  = (const float*)d_in[3];
  const float* e1b1  = (const float*)d_in[4];
  const float* e1w2  = (const float*)d_in[5];
  const float* e1b2  = (const float*)d_in[6];
  const float* root1 = (const float*)d_in[7];
  const float* bias1 = (const float*)d_in[8];
  const float* e2w1  = (const float*)d_in[9];
  const float* e2b1  = (const float*)d_in[10];
  const float* e2w2  = (const float*)d_in[11];
  const float* e2b2  = (const float*)d_in[12];
  const float* root2 = (const float*)d_in[13];
  const float* bias2 = (const float*)d_in[14];
  const float* linw  = (const float*)d_in[15];
  const float* linb  = (const float*)d_in[16];
  const int* srcp = ei;
  const int* dstp = ei + E_EDGES;

  char* ws = (char*)d_ws;
  size_t off = 0;
  auto alloc = [&](size_t bytes) { void* p = ws + off; off += (bytes + 255) & ~(size_t)255; return p; };
  unsigned short* h1buf = (unsigned short*)alloc((size_t)E_PAD*1024*2);   // 205 MB
  unsigned short* w2t   = (unsigned short*)alloc((size_t)1024*1024*2);
  float* agg  = (float*)alloc((size_t)N_NODES*32*4);
  float* cnt  = (float*)alloc((size_t)N_NODES*4);
  float* out1 = (float*)alloc((size_t)N_NODES*32*4);
  float* hbuf = (float*)alloc((size_t)N_NODES*32*4);
  (void)ws_size; (void)n_in; (void)in_sizes; (void)out_size;

  hipMemsetAsync(agg, 0, (size_t)N_NODES*32*4, stream);
  hipMemsetAsync(cnt, 0, (size_t)N_NODES*4, stream);
  count_kernel<<<(E_EDGES + 255)/256, 256, 0, stream>>>(dstp, cnt);

  const int gemm_grid = E_PAD/64;   // 1564

  // ---- layer 1 ----
  transpose_w2_kernel<<<1024, 256, 0, stream>>>(e1w2, w2t);
  edge_mlp1_kernel<<<E_PAD/16, 256, 0, stream>>>(ea, e1w1, e1b1, h1buf);
  gemm_scatter_kernel<<<gemm_grid, 512, 0, stream>>>(h1buf, w2t, e1b2, x, srcp, dstp, agg);
  node_update_kernel<<<(N_NODES*32 + 255)/256, 256, 0, stream>>>(agg, cnt, x, root1, bias1, out1);

  // ---- layer 2 ----
  hipMemsetAsync(agg, 0, (size_t)N_NODES*32*4, stream);
  transpose_w2_kernel<<<1024, 256, 0, stream>>>(e2w2, w2t);
  edge_mlp1_kernel<<<E_PAD/16, 256, 0, stream>>>(ea, e2w1, e2b1, h1buf);
  gemm_scatter_kernel<<<gemm_grid, 512, 0, stream>>>(h1buf, w2t, e2b2, out1, srcp, dstp, agg);
  node_update_kernel<<<(N_NODES*32 + 255)/256, 256, 0, stream>>>(agg, cnt, out1, root2, bias2, hbuf);

  final_linear_kernel<<<(N_NODES*10 + 255)/256, 256, 0, stream>>>(hbuf, linw, linb, (float*)d_out);
}

// Round 8
// 681.017 us; speedup vs baseline: 1.6737x; 1.6737x over previous
//
#include <hip/hip_runtime.h>

typedef __attribute__((ext_vector_type(8))) short sh8;       // 8 bf16 (4 VGPRs)
typedef __attribute__((ext_vector_type(4))) float f32x4;

#define E_EDGES 100000
#define E_PAD   100096   // 782 * 128
#define N_NODES 20000

__device__ __forceinline__ unsigned short f2bf(float f) {
  union { float f; unsigned int u; } v; v.f = f;
  unsigned int r = v.u + 0x7FFFu + ((v.u >> 16) & 1u);   // RNE
  return (unsigned short)(r >> 16);
}

__device__ __forceinline__ void async16(const void* g, void* l) {
  __builtin_amdgcn_global_load_lds((const __attribute__((address_space(1))) unsigned int*)g,
                                   (__attribute__((address_space(3))) unsigned int*)l,
                                   16, 0, 0);
}

// ---- w2 (f32 [k=1024][n=1024]) -> w2b: MFMA-fragment-major bf16 blocked
// layout [n/16][k/8][16][8]; a B-frag load becomes one coalesced 1KB/wave. ----
__global__ void transpose_w2_kernel(const float* __restrict__ w2, unsigned short* __restrict__ w2b) {
  __shared__ float tile[32][33];
  int b = blockIdx.x;                 // 32x32 tiles
  int bx = b & 31, by = b >> 5;
  int lx = threadIdx.x & 31, ly = threadIdx.x >> 5;   // 32 x 8
#pragma unroll
  for (int j = 0; j < 4; ++j)
    tile[ly + j*8][lx] = w2[(size_t)(by*32 + ly + j*8)*1024 + bx*32 + lx];   // tile[kw][nw]
  __syncthreads();
#pragma unroll
  for (int j = 0; j < 4; ++j) {
    int n = bx*32 + ly + j*8;
    int k = by*32 + lx;
    size_t idx = ((size_t)(n >> 4)*128 + (k >> 3))*128 + (n & 15)*8 + (k & 7);
    w2b[idx] = f2bf(tile[lx][ly + j*8]);
  }
}

// ---- h1 = relu(ea @ w1 + b1) -> bf16 [E_PAD][1024]; 16 edges per block ----
__global__ __launch_bounds__(256)
void edge_mlp1_kernel(const float* __restrict__ ea, const float* __restrict__ w1,
                      const float* __restrict__ b1, unsigned short* __restrict__ h1) {
  __shared__ float eas[16][16];
  const int tid = threadIdx.x;
  const int e0 = blockIdx.x * 16;
  {
    int g = tid >> 4, d = tid & 15;
    int ge = e0 + g;
    eas[g][d] = (ge < E_EDGES) ? ea[(size_t)ge*16 + d] : 0.f;
  }
  __syncthreads();
  const int c0 = tid * 4;
  float4 bb = *(const float4*)(b1 + c0);
  float4 acc[16];
#pragma unroll
  for (int g = 0; g < 16; ++g) acc[g] = bb;
#pragma unroll
  for (int d = 0; d < 16; ++d) {
    float4 w = *(const float4*)(w1 + (size_t)d*1024 + c0);
#pragma unroll
    for (int g = 0; g < 16; ++g) {
      float ev = eas[g][d];
      acc[g].x += ev*w.x; acc[g].y += ev*w.y; acc[g].z += ev*w.z; acc[g].w += ev*w.w;
    }
  }
#pragma unroll
  for (int g = 0; g < 16; ++g) {
    ushort4 o;
    if (e0 + g < E_EDGES) {
      o.x = f2bf(fmaxf(acc[g].x, 0.f)); o.y = f2bf(fmaxf(acc[g].y, 0.f));
      o.z = f2bf(fmaxf(acc[g].z, 0.f)); o.w = f2bf(fmaxf(acc[g].w, 0.f));
    } else {
      o.x = o.y = o.z = o.w = 0;
    }
    *(ushort4*)(h1 + (size_t)(e0 + g)*1024 + c0) = o;
  }
}

// ---- cnt[dst] += 1 ----
__global__ void count_kernel(const int* __restrict__ dst, float* __restrict__ cnt) {
  int t = blockIdx.x*256 + threadIdx.x;
  if (t < E_EDGES) atomicAdd(&cnt[dst[t]], 1.0f);
}

// ---- big GEMM: R4 champion structure (128^2 tile, 4 waves, 2-barrier K-loop)
// but ONLY A staged in LDS (16 KB); B-frags read directly from L2 via the
// fragment-major blocked w2b (coalesced 1KB/load). LDS ~20 KB -> up to 8
// blocks/CU for TLP latency hiding. ----
__global__ __launch_bounds__(256, 4)
void gemm_scatter_kernel(const unsigned short* __restrict__ h1,
                         const unsigned short* __restrict__ w2b,
                         const float* __restrict__ b2,
                         const float* __restrict__ xin,
                         const int* __restrict__ src,
                         const int* __restrict__ dst,
                         float* __restrict__ agg) {
  // Als @0 (16384 B, K-loop) | msgbuf @0 (16896 B, epilogue alias)
  // xg @17408 (2048 B) | dsts @19456 (512 B)  -> 19968 B total
  __shared__ __align__(16) unsigned char smem[19968];
  unsigned short* Als = (unsigned short*)smem;            // [128][64] swizzled
  float* msgbuf = (float*)smem;                           // [128][33] (epilogue)
  float (*xg)[4] = (float (*)[4])(smem + 17408);
  int* dsts = (int*)(smem + 19456);

  const int tid  = threadIdx.x;
  const int wave = tid >> 6, lane = tid & 63;
  const int wm = wave >> 1, wn = wave & 1;               // 2x2 waves, 64x64 each
  const int lr = lane >> 4, lc = lane & 15;
  // XCD-bijective swizzle: grid 6256 = 8 XCD * 782
  const int logical = (blockIdx.x & 7) * 782 + (blockIdx.x >> 3);
  const int tile_m = logical >> 3, tile_n = logical & 7;
  const int e0 = tile_m * 128, n0 = tile_n * 128;

  if (tid < 128) {                                       // gather x[src]
    int ge = e0 + tid;
    float4 v = make_float4(0.f, 0.f, 0.f, 0.f);
    if (ge < E_EDGES) {
      int s = src[ge];
      v = *(const float4*)(xin + (size_t)s*32 + tile_n*4);
    }
    *(float4*)xg[tid] = v;
  } else {
    int e = tid - 128;
    int ge = e0 + e;
    dsts[e] = (ge < E_EDGES) ? dst[ge] : -1;
  }

  f32x4 acc[4][4];
#pragma unroll
  for (int i = 0; i < 4; ++i)
#pragma unroll
    for (int j = 0; j < 4; ++j) acc[i][j] = (f32x4){0.f,0.f,0.f,0.f};

  const unsigned short* Ag = h1 + (size_t)e0*1024;
  const int rj     = lane >> 3;                          // row within 8-row group
  const int srow   = wave*32 + rj;                       // + j*8
  const int scol   = 8*((lane & 7) ^ rj);                // pre-swizzled source col
  const int swzb   = (lc & 7) << 4;                      // read-side byte XOR

  // B frag base: group g = tile_n*8 + wn*4 + ni; kgrp = kt*8 + kk*4 + lr
  // byte addr = (g*128 + kgrp)*256 + lc*16  -> contiguous 1KB per wave-load
  const char* Bb = (const char*)w2b
                 + (size_t)(tile_n*8 + wn*4)*32768 + lr*256 + lc*16;

  for (int kt = 0; kt < 16; ++kt) {
    __syncthreads();                       // prev-tile readers done
#pragma unroll
    for (int j = 0; j < 4; ++j)
      async16(Ag + (size_t)(srow + j*8)*1024 + kt*64 + scol, &Als[wave*2048 + j*512]);
    __syncthreads();                       // vmcnt(0) drain: A tile resident
#pragma unroll
    for (int kk = 0; kk < 2; ++kk) {
      sh8 av[4], bv[4];
#pragma unroll
      for (int ni = 0; ni < 4; ++ni)
        bv[ni] = *(const sh8*)(Bb + ni*32768 + kt*2048 + kk*1024);   // L2-resident B
#pragma unroll
      for (int mi = 0; mi < 4; ++mi)
        av[mi] = *(const sh8*)((const char*)Als + (wm*64 + mi*16 + lc)*128 + ((kk*64 + lr*16) ^ swzb));
#pragma unroll
      for (int mi = 0; mi < 4; ++mi)
#pragma unroll
        for (int ni = 0; ni < 4; ++ni)
          acc[mi][ni] = __builtin_amdgcn_mfma_f32_16x16x32_bf16(av[mi], bv[ni], acc[mi][ni], 0, 0, 0);
    }
  }

  // epilogue: h2 = acc + b2;  partial_msg[e][o] = sum_di xg[e][di] * h2[e][di*32+o]
  float b2c[4];
#pragma unroll
  for (int ni = 0; ni < 4; ++ni) b2c[ni] = b2[n0 + wn*64 + ni*16 + lc];

  float ms0[4][4], ms1[4][4];
#pragma unroll
  for (int mi = 0; mi < 4; ++mi)
#pragma unroll
    for (int r = 0; r < 4; ++r) {
      int e = wm*64 + mi*16 + lr*4 + r;
      float x0 = xg[e][2*wn], x1 = xg[e][2*wn + 1];
      ms0[mi][r] = (acc[mi][0][r] + b2c[0])*x0 + (acc[mi][2][r] + b2c[2])*x1;   // o = lc
      ms1[mi][r] = (acc[mi][1][r] + b2c[1])*x0 + (acc[mi][3][r] + b2c[3])*x1;   // o = lc+16
    }

  __syncthreads();   // K-loop LDS dead from here; msgbuf aliases it
  if (wn == 0) {
#pragma unroll
    for (int mi = 0; mi < 4; ++mi)
#pragma unroll
      for (int r = 0; r < 4; ++r) {
        int e = wm*64 + mi*16 + lr*4 + r;
        msgbuf[e*33 + lc]      = ms0[mi][r];
        msgbuf[e*33 + lc + 16] = ms1[mi][r];
      }
  }
  __syncthreads();
  if (wn == 1) {
#pragma unroll
    for (int mi = 0; mi < 4; ++mi)
#pragma unroll
      for (int r = 0; r < 4; ++r) {
        int e = wm*64 + mi*16 + lr*4 + r;
        msgbuf[e*33 + lc]      += ms0[mi][r];
        msgbuf[e*33 + lc + 16] += ms1[mi][r];
      }
  }
  __syncthreads();
  for (int t = tid; t < 128*32; t += 256) {
    int e = t >> 5, o = t & 31;
    int dn = dsts[e];
    if (dn >= 0) atomicAdd(&agg[(size_t)dn*32 + o], msgbuf[e*33 + o]);
  }
}

// ---- node update: out = relu(agg/max(cnt,1) + x@root + bias) ----
__global__ void node_update_kernel(const float* __restrict__ agg, const float* __restrict__ cnt,
                                   const float* __restrict__ xin, const float* __restrict__ root,
                                   const float* __restrict__ bias, float* __restrict__ outp) {
  int t = blockIdx.x*256 + threadIdx.x;
  if (t >= N_NODES*32) return;
  int n = t >> 5, i = t & 31;
  const float* xr = xin + (size_t)n*32;
  float s = bias[i];
#pragma unroll
  for (int j = 0; j < 32; ++j) s += xr[j]*root[j*32 + i];
  float c = cnt[n]; c = c > 1.f ? c : 1.f;
  float v = agg[t]/c + s;
  outp[t] = fmaxf(v, 0.f);
}

// ---- final: out = h @ lin_w + lin_b ----
__global__ void final_linear_kernel(const float* __restrict__ h, const float* __restrict__ lw,
                                    const float* __restrict__ lb, float* __restrict__ out) {
  int t = blockIdx.x*256 + threadIdx.x;
  if (t >= N_NODES*10) return;
  int n = t / 10, k = t % 10;
  const float* hr = h + (size_t)n*32;
  float s = lb[k];
#pragma unroll
  for (int i = 0; i < 32; ++i) s += hr[i]*lw[i*10 + k];
  out[t] = s;
}

extern "C" void kernel_launch(void* const* d_in, const int* in_sizes, int n_in,
                              void* d_out, int out_size, void* d_ws, size_t ws_size,
                              hipStream_t stream) {
  const float* x     = (const float*)d_in[0];
  const int*   ei    = (const int*)d_in[1];
  const float* ea    = (const float*)d_in[2];
  const float* e1w1  = (const float*)d_in[3];
  const float* e1b1  = (const float*)d_in[4];
  const float* e1w2  = (const float*)d_in[5];
  const float* e1b2  = (const float*)d_in[6];
  const float* root1 = (const float*)d_in[7];
  const float* bias1 = (const float*)d_in[8];
  const float* e2w1  = (const float*)d_in[9];
  const float* e2b1  = (const float*)d_in[10];
  const float* e2w2  = (const float*)d_in[11];
  const float* e2b2  = (const float*)d_in[12];
  const float* root2 = (const float*)d_in[13];
  const float* bias2 = (const float*)d_in[14];
  const float* linw  = (const float*)d_in[15];
  const float* linb  = (const float*)d_in[16];
  const int* srcp = ei;
  const int* dstp = ei + E_EDGES;

  char* ws = (char*)d_ws;
  size_t off = 0;
  auto alloc = [&](size_t bytes) { void* p = ws + off; off += (bytes + 255) & ~(size_t)255; return p; };
  unsigned short* h1buf = (unsigned short*)alloc((size_t)E_PAD*1024*2);   // 205 MB
  unsigned short* w2b   = (unsigned short*)alloc((size_t)1024*1024*2);
  float* agg  = (float*)alloc((size_t)N_NODES*32*4);
  float* cnt  = (float*)alloc((size_t)N_NODES*4);
  float* out1 = (float*)alloc((size_t)N_NODES*32*4);
  float* hbuf = (float*)alloc((size_t)N_NODES*32*4);
  (void)ws_size; (void)n_in; (void)in_sizes; (void)out_size;

  hipMemsetAsync(agg, 0, (size_t)N_NODES*32*4, stream);
  hipMemsetAsync(cnt, 0, (size_t)N_NODES*4, stream);
  count_kernel<<<(E_EDGES + 255)/256, 256, 0, stream>>>(dstp, cnt);

  // ---- layer 1 ----
  transpose_w2_kernel<<<1024, 256, 0, stream>>>(e1w2, w2b);
  edge_mlp1_kernel<<<E_PAD/16, 256, 0, stream>>>(ea, e1w1, e1b1, h1buf);
  gemm_scatter_kernel<<<(E_PAD/128)*8, 256, 0, stream>>>(h1buf, w2b, e1b2, x, srcp, dstp, agg);
  node_update_kernel<<<(N_NODES*32 + 255)/256, 256, 0, stream>>>(agg, cnt, x, root1, bias1, out1);

  // ---- layer 2 ----
  hipMemsetAsync(agg, 0, (size_t)N_NODES*32*4, stream);
  transpose_w2_kernel<<<1024, 256, 0, stream>>>(e2w2, w2b);
  edge_mlp1_kernel<<<E_PAD/16, 256, 0, stream>>>(ea, e2w1, e2b1, h1buf);
  gemm_scatter_kernel<<<(E_PAD/128)*8, 256, 0, stream>>>(h1buf, w2b, e2b2, out1, srcp, dstp, agg);
  node_update_kernel<<<(N_NODES*32 + 255)/256, 256, 0, stream>>>(agg, cnt, out1, root2, bias2, hbuf);

  final_linear_kernel<<<(N_NODES*10 + 255)/256, 256, 0, stream>>>(hbuf, linw, linb, (float*)d_out);
}